// Round 1
// baseline (652.936 us; speedup 1.0000x reference)
//
#include <hip/hip_runtime.h>

#define N_NODES 50000
#define N_EDGES 600000
#define HID 128

// ---------------- preprocessing kernels ----------------

__global__ __launch_bounds__(256) void init_k(float* deg, int* cnt, float* cs, int n) {
    int i = blockIdx.x * 256 + threadIdx.x;
    if (i < n) { deg[i] = 1.0f; cnt[i] = 0; }
    if (i < HID) cs[i] = 0.0f;
}

__global__ __launch_bounds__(256) void edge_deg_k(const int* __restrict__ edges,
                                                  const float* __restrict__ attr,
                                                  float* deg, int* cnt) {
    int e = blockIdx.x * 256 + threadIdx.x;
    if (e < N_EDGES) {
        int c = edges[N_EDGES + e];          // target
        atomicAdd(&deg[c], attr[e]);
        atomicAdd(&cnt[c], 1);
    }
}

__global__ __launch_bounds__(256) void rsqrt_k(const float* __restrict__ deg, float* dinv, int n) {
    int i = blockIdx.x * 256 + threadIdx.x;
    if (i < n) dinv[i] = rsqrtf(deg[i]);     // deg >= 1 always (self-loop)
}

// exclusive scan, 3 kernels, 256-wide blocks
__global__ __launch_bounds__(256) void scan1_k(const int* __restrict__ cnt, int* offs, int* bsum, int n) {
    __shared__ int s[256];
    int tid = threadIdx.x;
    int i = blockIdx.x * 256 + tid;
    int v = (i < n) ? cnt[i] : 0;
    s[tid] = v; __syncthreads();
    for (int d = 1; d < 256; d <<= 1) {
        int t = (tid >= d) ? s[tid - d] : 0;
        __syncthreads();
        s[tid] += t;
        __syncthreads();
    }
    if (i < n) offs[i] = s[tid] - v;         // block-local exclusive
    if (tid == 255) bsum[blockIdx.x] = s[255];
}

__global__ __launch_bounds__(256) void scan2_k(int* bsum, int nb) {
    __shared__ int s[256];
    int t = threadIdx.x;
    int v = (t < nb) ? bsum[t] : 0;
    s[t] = v; __syncthreads();
    for (int d = 1; d < 256; d <<= 1) {
        int u = (t >= d) ? s[t - d] : 0;
        __syncthreads();
        s[t] += u;
        __syncthreads();
    }
    if (t < nb) bsum[t] = s[t] - v;          // exclusive in-place
}

__global__ __launch_bounds__(256) void scan3_k(int* offs, const int* __restrict__ bsum, int* cursor, int n) {
    int i = blockIdx.x * 256 + threadIdx.x;
    if (i < n) {
        int v = offs[i] + bsum[blockIdx.x];
        offs[i] = v;
        cursor[i] = v;
    }
}

__global__ __launch_bounds__(256) void fill_k(const int* __restrict__ edges,
                                              const float* __restrict__ attr,
                                              const float* __restrict__ dinv,
                                              int* cursor, int* srow, float* sw) {
    int e = blockIdx.x * 256 + threadIdx.x;
    if (e < N_EDGES) {
        int r = edges[e];                    // source
        int c = edges[N_EDGES + e];          // target
        float w = dinv[r] * attr[e] * dinv[c];
        int p = atomicAdd(&cursor[c], 1);
        srow[p] = r;
        sw[p]  = w;
    }
}

// ---------------- GEMM: H[n x 128] = X[n x 128] @ W[128 x 128] ----------------

__global__ __launch_bounds__(256) void gemm128_k(const float* __restrict__ X,
                                                 const float* __restrict__ W,
                                                 float* __restrict__ H, int nrows) {
    __shared__ float Xs[64][129];
    int row0 = blockIdx.x * 64;
    int tid = threadIdx.x;

    // stage 64x128 tile of X
    #pragma unroll
    for (int it = 0; it < 8; ++it) {
        int idx = it * 256 + tid;            // 0..2047 float4 slots
        int r  = idx >> 5;
        int c4 = (idx & 31) << 2;
        int gr = row0 + r;
        float4 v = make_float4(0.f, 0.f, 0.f, 0.f);
        if (gr < nrows) v = *(const float4*)(X + (size_t)gr * HID + c4);
        Xs[r][c4 + 0] = v.x; Xs[r][c4 + 1] = v.y;
        Xs[r][c4 + 2] = v.z; Xs[r][c4 + 3] = v.w;
    }
    __syncthreads();

    int tx = tid & 31, ty = tid >> 5;
    int j0 = tx * 4;
    int r0 = ty * 8;
    float acc[8][4];
    #pragma unroll
    for (int r = 0; r < 8; ++r)
        #pragma unroll
        for (int j = 0; j < 4; ++j) acc[r][j] = 0.f;

    #pragma unroll 4
    for (int k = 0; k < 128; ++k) {
        float4 w4 = *(const float4*)(W + k * HID + j0);
        float xs[8];
        #pragma unroll
        for (int r = 0; r < 8; ++r) xs[r] = Xs[r0 + r][k];
        #pragma unroll
        for (int r = 0; r < 8; ++r) {
            acc[r][0] = fmaf(xs[r], w4.x, acc[r][0]);
            acc[r][1] = fmaf(xs[r], w4.y, acc[r][1]);
            acc[r][2] = fmaf(xs[r], w4.z, acc[r][2]);
            acc[r][3] = fmaf(xs[r], w4.w, acc[r][3]);
        }
    }

    #pragma unroll
    for (int r = 0; r < 8; ++r) {
        int gr = row0 + r0 + r;
        if (gr < nrows)
            *(float4*)(H + (size_t)gr * HID + j0) =
                make_float4(acc[r][0], acc[r][1], acc[r][2], acc[r][3]);
    }
}

// ---------------- aggregation: one wave per node ----------------
// xout[i] = relu( bias + (xprev? xprev[i]:0) + dinv[i]^2 * h[i] + sum_e w_e * h[src_e] )

__global__ __launch_bounds__(256) void aggregate_k(const float* __restrict__ h,
                                                   const int* __restrict__ offs,
                                                   const int* __restrict__ srow,
                                                   const float* __restrict__ sw,
                                                   const float* __restrict__ dinv,
                                                   const float* __restrict__ bias,
                                                   const float* __restrict__ xprev,
                                                   float* __restrict__ xout, int n) {
    int w    = (blockIdx.x * 256 + threadIdx.x) >> 6;
    int lane = threadIdx.x & 63;
    if (w >= n) return;
    int c = lane * 2;

    float2 acc = *(const float2*)(bias + c);
    if (xprev) {
        float2 xp = *(const float2*)(xprev + (size_t)w * HID + c);
        acc.x += xp.x; acc.y += xp.y;
    }
    float di = dinv[w];
    float d2 = di * di;
    {
        float2 hv = *(const float2*)(h + (size_t)w * HID + c);
        acc.x = fmaf(hv.x, d2, acc.x);
        acc.y = fmaf(hv.y, d2, acc.y);
    }
    int e0 = offs[w];
    int e1 = (w + 1 < n) ? offs[w + 1] : N_EDGES;
    for (int e = e0; e < e1; ++e) {
        int   r  = srow[e];
        float wt = sw[e];
        float2 hv = *(const float2*)(h + (size_t)r * HID + c);
        acc.x = fmaf(hv.x, wt, acc.x);
        acc.y = fmaf(hv.y, wt, acc.y);
    }
    acc.x = fmaxf(acc.x, 0.f);
    acc.y = fmaxf(acc.y, 0.f);
    *(float2*)(xout + (size_t)w * HID + c) = acc;
}

// ---------------- final head: out = colsum(x)/N @ Wfc + bfc ----------------

__global__ __launch_bounds__(128) void colsum_k(const float* __restrict__ x, float* cs, int n) {
    int col = threadIdx.x;  // 128 threads
    float acc = 0.f;
    for (int r = blockIdx.x; r < n; r += gridDim.x)
        acc += x[(size_t)r * HID + col];
    atomicAdd(&cs[col], acc);
}

__global__ __launch_bounds__(128) void final_k(const float* __restrict__ cs,
                                               const float* __restrict__ Wfc,
                                               const float* __restrict__ bfc,
                                               float* __restrict__ out) {
    __shared__ float s0[128], s1[128];
    int k = threadIdx.x;
    float c = cs[k];
    s0[k] = c * Wfc[k * 2 + 0];
    s1[k] = c * Wfc[k * 2 + 1];
    __syncthreads();
    for (int d = 64; d > 0; d >>= 1) {
        if (k < d) { s0[k] += s0[k + d]; s1[k] += s1[k + d]; }
        __syncthreads();
    }
    if (k == 0) {
        out[0] = s0[0] / (float)N_NODES + bfc[0];
        out[1] = s1[0] / (float)N_NODES + bfc[1];
    }
}

// ---------------- host ----------------

extern "C" void kernel_launch(void* const* d_in, const int* in_sizes, int n_in,
                              void* d_out, int out_size, void* d_ws, size_t ws_size,
                              hipStream_t stream) {
    const float* node  = (const float*)d_in[0];
    const int*   edges = (const int*)d_in[1];     // [2, E] int32
    const float* attr  = (const float*)d_in[2];
    const float* W1    = (const float*)d_in[3];
    const float* b1    = (const float*)d_in[4];
    const float* Ws    = (const float*)d_in[5];   // [4,128,128]
    const float* bs    = (const float*)d_in[6];   // [4,128]
    const float* Wfc   = (const float*)d_in[7];   // [128,2]
    const float* bfc   = (const float*)d_in[8];
    float* out = (float*)d_out;

    char* ws = (char*)d_ws;
    const size_t HN = (size_t)N_NODES * HID * sizeof(float);   // 25.6 MB
    float* h     = (float*)(ws);
    float* xa    = (float*)(ws + HN);
    float* xb    = (float*)(ws + 2 * HN);
    char*  p     = ws + 3 * HN;
    float* deg   = (float*)p;            p += N_NODES * 4;
    float* dinv  = (float*)p;            p += N_NODES * 4;
    int*   cnt   = (int*)p;              p += N_NODES * 4;
    int*   offs  = (int*)p;              p += N_NODES * 4;
    int*   cursor= (int*)p;              p += N_NODES * 4;
    int*   bsum  = (int*)p;              p += 1024;
    int*   srow  = (int*)p;              p += (size_t)N_EDGES * 4;
    float* sw    = (float*)p;            p += (size_t)N_EDGES * 4;
    float* cs    = (float*)p;            p += 512;

    const int NB_N = (N_NODES + 255) / 256;   // 196
    const int NB_E = (N_EDGES + 255) / 256;   // 2344

    // preprocessing: degrees, dinv, CSR-by-destination
    hipLaunchKernelGGL(init_k,    dim3(NB_N), dim3(256), 0, stream, deg, cnt, cs, N_NODES);
    hipLaunchKernelGGL(edge_deg_k,dim3(NB_E), dim3(256), 0, stream, edges, attr, deg, cnt);
    hipLaunchKernelGGL(rsqrt_k,   dim3(NB_N), dim3(256), 0, stream, deg, dinv, N_NODES);
    hipLaunchKernelGGL(scan1_k,   dim3(NB_N), dim3(256), 0, stream, cnt, offs, bsum, N_NODES);
    hipLaunchKernelGGL(scan2_k,   dim3(1),    dim3(256), 0, stream, bsum, NB_N);
    hipLaunchKernelGGL(scan3_k,   dim3(NB_N), dim3(256), 0, stream, offs, bsum, cursor, N_NODES);
    hipLaunchKernelGGL(fill_k,    dim3(NB_E), dim3(256), 0, stream, edges, attr, dinv, cursor, srow, sw);

    const int GB = (N_NODES + 63) / 64;       // 782
    const int AB = (N_NODES * 64) / 256;      // 12500

    // layer 1: h = node @ W1 ; xa = relu(agg + b1)
    hipLaunchKernelGGL(gemm128_k,  dim3(GB), dim3(256), 0, stream, node, W1, h, N_NODES);
    hipLaunchKernelGGL(aggregate_k,dim3(AB), dim3(256), 0, stream, h, offs, srow, sw, dinv,
                       b1, (const float*)nullptr, xa, N_NODES);

    // 4 residual steps
    float* xc = xa;
    float* xn = xb;
    for (int i = 0; i < 4; ++i) {
        hipLaunchKernelGGL(gemm128_k,  dim3(GB), dim3(256), 0, stream,
                           xc, Ws + (size_t)i * HID * HID, h, N_NODES);
        hipLaunchKernelGGL(aggregate_k,dim3(AB), dim3(256), 0, stream, h, offs, srow, sw, dinv,
                           bs + (size_t)i * HID, xc, xn, N_NODES);
        float* t = xc; xc = xn; xn = t;
    }

    // head
    hipLaunchKernelGGL(colsum_k, dim3(512), dim3(128), 0, stream, xc, cs, N_NODES);
    hipLaunchKernelGGL(final_k,  dim3(1),   dim3(128), 0, stream, cs, Wfc, bfc, out);
}

// Round 2
// 565.408 us; speedup vs baseline: 1.1548x; 1.1548x over previous
//
#include <hip/hip_runtime.h>

#define N_NODES 50000
#define N_EDGES 600000
#define HID 128

typedef __attribute__((ext_vector_type(8))) short bf16x8;
typedef __attribute__((ext_vector_type(4))) float f32x4;

__device__ __forceinline__ float bf2f(unsigned short u) {
    return __uint_as_float(((unsigned int)u) << 16);
}
__device__ __forceinline__ unsigned short f2bf(float f) {
    unsigned int u = __float_as_uint(f);
    u = (u + 0x7FFFu + ((u >> 16) & 1u)) >> 16;   // RNE
    return (unsigned short)u;
}

// ---------------- preprocessing kernels ----------------

__global__ __launch_bounds__(256) void init_k(float* deg, int* cnt, float* cs, int n) {
    int i = blockIdx.x * 256 + threadIdx.x;
    if (i < n) { deg[i] = 1.0f; cnt[i] = 0; }
    if (i < HID) cs[i] = 0.0f;
}

__global__ __launch_bounds__(256) void edge_deg_k(const int* __restrict__ edges,
                                                  const float* __restrict__ attr,
                                                  float* deg, int* cnt) {
    int e = blockIdx.x * 256 + threadIdx.x;
    if (e < N_EDGES) {
        int c = edges[N_EDGES + e];          // target
        atomicAdd(&deg[c], attr[e]);
        atomicAdd(&cnt[c], 1);
    }
}

__global__ __launch_bounds__(256) void rsqrt_k(const float* __restrict__ deg, float* dinv, int n) {
    int i = blockIdx.x * 256 + threadIdx.x;
    if (i < n) dinv[i] = rsqrtf(deg[i]);     // deg >= 1 always (self-loop)
}

__global__ __launch_bounds__(256) void scan1_k(const int* __restrict__ cnt, int* offs, int* bsum, int n) {
    __shared__ int s[256];
    int tid = threadIdx.x;
    int i = blockIdx.x * 256 + tid;
    int v = (i < n) ? cnt[i] : 0;
    s[tid] = v; __syncthreads();
    for (int d = 1; d < 256; d <<= 1) {
        int t = (tid >= d) ? s[tid - d] : 0;
        __syncthreads();
        s[tid] += t;
        __syncthreads();
    }
    if (i < n) offs[i] = s[tid] - v;
    if (tid == 255) bsum[blockIdx.x] = s[255];
}

__global__ __launch_bounds__(256) void scan2_k(int* bsum, int nb) {
    __shared__ int s[256];
    int t = threadIdx.x;
    int v = (t < nb) ? bsum[t] : 0;
    s[t] = v; __syncthreads();
    for (int d = 1; d < 256; d <<= 1) {
        int u = (t >= d) ? s[t - d] : 0;
        __syncthreads();
        s[t] += u;
        __syncthreads();
    }
    if (t < nb) bsum[t] = s[t] - v;
}

__global__ __launch_bounds__(256) void scan3_k(int* offs, const int* __restrict__ bsum, int* cursor, int n) {
    int i = blockIdx.x * 256 + threadIdx.x;
    if (i < n) {
        int v = offs[i] + bsum[blockIdx.x];
        offs[i] = v;
        cursor[i] = v;
    }
}

__global__ __launch_bounds__(256) void fill_k(const int* __restrict__ edges,
                                              const float* __restrict__ attr,
                                              const float* __restrict__ dinv,
                                              int* cursor, int2* __restrict__ epk) {
    int e = blockIdx.x * 256 + threadIdx.x;
    if (e < N_EDGES) {
        int r = edges[e];                    // source
        int c = edges[N_EDGES + e];          // target
        float w = dinv[r] * attr[e] * dinv[c];
        int p = atomicAdd(&cursor[c], 1);
        epk[p] = make_int2(r, __float_as_int(w));
    }
}

// W^T bf16 hi/lo split for 5 layers: Wt[l][n][k] = W_l[k][n]
__global__ __launch_bounds__(256) void prep_w_k(const float* __restrict__ W1,
                                                const float* __restrict__ Ws,
                                                unsigned short* __restrict__ Wt_hi,
                                                unsigned short* __restrict__ Wt_lo) {
    int i = blockIdx.x * 256 + threadIdx.x;
    if (i >= 5 * 16384) return;
    int l = i >> 14;
    int r = i & 16383;
    int n = r >> 7;
    int k = r & 127;
    const float* src = (l == 0) ? W1 : (Ws + (size_t)(l - 1) * 16384);
    float w = src[k * 128 + n];
    unsigned short hi = f2bf(w);
    unsigned short lo = f2bf(w - bf2f(hi));
    Wt_hi[i] = hi;
    Wt_lo[i] = lo;
}

// fp32 -> bf16 bulk convert (4 elems/thread)
__global__ __launch_bounds__(256) void cvt_bf_k(const float* __restrict__ x,
                                                unsigned short* __restrict__ y, int n4) {
    int i = blockIdx.x * 256 + threadIdx.x;
    if (i < n4) {
        float4 v = ((const float4*)x)[i];
        ushort4 o;
        o.x = f2bf(v.x); o.y = f2bf(v.y); o.z = f2bf(v.z); o.w = f2bf(v.w);
        ((ushort4*)y)[i] = o;
    }
}

// ---------------- MFMA GEMM: H[n x 128] = A[n x 128] @ (W_hi + W_lo) ----------------
// A bf16 row-major; B given as W^T [n][k] bf16 (hi/lo); H bf16 out.

__global__ __launch_bounds__(256) void mfma_gemm_k(const unsigned short* __restrict__ A,
                                                   const unsigned short* __restrict__ Bh,
                                                   const unsigned short* __restrict__ Bl,
                                                   unsigned short* __restrict__ H, int nrows) {
    int wid  = threadIdx.x >> 6;
    int lane = threadIdx.x & 63;
    int row0 = blockIdx.x * 64 + wid * 16;
    int rl = lane & 15;          // A row within tile / B col
    int kg = lane >> 4;          // k-group (8 elems each)

    int row = row0 + rl;
    int ar  = row < nrows ? row : nrows - 1;

    bf16x8 af[4];
    #pragma unroll
    for (int kt = 0; kt < 4; ++kt)
        af[kt] = *(const bf16x8*)(A + (size_t)ar * HID + kt * 32 + kg * 8);

    f32x4 acc[8];
    #pragma unroll
    for (int nt = 0; nt < 8; ++nt) acc[nt] = (f32x4){0.f, 0.f, 0.f, 0.f};

    #pragma unroll
    for (int nt = 0; nt < 8; ++nt) {
        #pragma unroll
        for (int kt = 0; kt < 4; ++kt) {
            size_t boff = (size_t)(nt * 16 + rl) * HID + kt * 32 + kg * 8;
            bf16x8 bh = *(const bf16x8*)(Bh + boff);
            acc[nt] = __builtin_amdgcn_mfma_f32_16x16x32_bf16(af[kt], bh, acc[nt], 0, 0, 0);
            bf16x8 bl = *(const bf16x8*)(Bl + boff);
            acc[nt] = __builtin_amdgcn_mfma_f32_16x16x32_bf16(af[kt], bl, acc[nt], 0, 0, 0);
        }
    }

    // D: col = lane&15, row = (lane>>4)*4 + reg
    #pragma unroll
    for (int nt = 0; nt < 8; ++nt) {
        #pragma unroll
        for (int r = 0; r < 4; ++r) {
            int orow = row0 + kg * 4 + r;
            if (orow < nrows)
                H[(size_t)orow * HID + nt * 16 + rl] = f2bf(acc[nt][r]);
        }
    }
}

// ---------------- aggregation: one wave per node, 2 edges/iter, bf16 gather ----------------
// xout[i] = relu( bias + xprev[i] + dinv[i]^2 * h[i] + sum_e w_e * h[src_e] )   (all bf16 in, fp32 accum)

__global__ __launch_bounds__(256) void aggregate_k(const unsigned short* __restrict__ h,
                                                   const int* __restrict__ offs,
                                                   const int2* __restrict__ epk,
                                                   const float* __restrict__ dinv,
                                                   const float* __restrict__ bias,
                                                   const unsigned short* __restrict__ xprev,
                                                   unsigned short* __restrict__ xout, int n) {
    int w = (blockIdx.x * 256 + threadIdx.x) >> 6;
    if (w >= n) return;
    int lane = threadIdx.x & 63;
    int half = lane >> 5;
    int c4 = (lane & 31) * 4;                // 4 bf16 columns per lane, 32 lanes = full row

    float a0 = 0.f, a1 = 0.f, a2 = 0.f, a3 = 0.f;
    int e0 = offs[w];
    int e1 = (w + 1 < n) ? offs[w + 1] : N_EDGES;

    for (int e = e0 + half; e < e1; e += 2) {
        int2 pk = epk[e];
        float wt = __int_as_float(pk.y);
        ushort4 hv = *(const ushort4*)(h + (size_t)pk.x * HID + c4);
        a0 = fmaf(bf2f(hv.x), wt, a0);
        a1 = fmaf(bf2f(hv.y), wt, a1);
        a2 = fmaf(bf2f(hv.z), wt, a2);
        a3 = fmaf(bf2f(hv.w), wt, a3);
    }

    a0 += __shfl_xor(a0, 32);
    a1 += __shfl_xor(a1, 32);
    a2 += __shfl_xor(a2, 32);
    a3 += __shfl_xor(a3, 32);

    if (half == 0) {
        float di = dinv[w];
        float d2 = di * di;
        ushort4 hw = *(const ushort4*)(h + (size_t)w * HID + c4);
        a0 = fmaf(bf2f(hw.x), d2, a0);
        a1 = fmaf(bf2f(hw.y), d2, a1);
        a2 = fmaf(bf2f(hw.z), d2, a2);
        a3 = fmaf(bf2f(hw.w), d2, a3);
        float4 b = *(const float4*)(bias + c4);
        a0 += b.x; a1 += b.y; a2 += b.z; a3 += b.w;
        if (xprev) {
            ushort4 xp = *(const ushort4*)(xprev + (size_t)w * HID + c4);
            a0 += bf2f(xp.x); a1 += bf2f(xp.y); a2 += bf2f(xp.z); a3 += bf2f(xp.w);
        }
        ushort4 o;
        o.x = f2bf(fmaxf(a0, 0.f));
        o.y = f2bf(fmaxf(a1, 0.f));
        o.z = f2bf(fmaxf(a2, 0.f));
        o.w = f2bf(fmaxf(a3, 0.f));
        *(ushort4*)(xout + (size_t)w * HID + c4) = o;
    }
}

// ---------------- final head ----------------

__global__ __launch_bounds__(128) void colsum_k(const unsigned short* __restrict__ x, float* cs, int n) {
    int col = threadIdx.x;  // 128 threads
    float acc = 0.f;
    for (int r = blockIdx.x; r < n; r += gridDim.x)
        acc += bf2f(x[(size_t)r * HID + col]);
    atomicAdd(&cs[col], acc);
}

__global__ __launch_bounds__(128) void final_k(const float* __restrict__ cs,
                                               const float* __restrict__ Wfc,
                                               const float* __restrict__ bfc,
                                               float* __restrict__ out) {
    __shared__ float s0[128], s1[128];
    int k = threadIdx.x;
    float c = cs[k];
    s0[k] = c * Wfc[k * 2 + 0];
    s1[k] = c * Wfc[k * 2 + 1];
    __syncthreads();
    for (int d = 64; d > 0; d >>= 1) {
        if (k < d) { s0[k] += s0[k + d]; s1[k] += s1[k + d]; }
        __syncthreads();
    }
    if (k == 0) {
        out[0] = s0[0] / (float)N_NODES + bfc[0];
        out[1] = s1[0] / (float)N_NODES + bfc[1];
    }
}

// ---------------- host ----------------

extern "C" void kernel_launch(void* const* d_in, const int* in_sizes, int n_in,
                              void* d_out, int out_size, void* d_ws, size_t ws_size,
                              hipStream_t stream) {
    const float* node  = (const float*)d_in[0];
    const int*   edges = (const int*)d_in[1];     // [2, E] int32
    const float* attr  = (const float*)d_in[2];
    const float* W1    = (const float*)d_in[3];
    const float* b1    = (const float*)d_in[4];
    const float* Ws    = (const float*)d_in[5];   // [4,128,128]
    const float* bs    = (const float*)d_in[6];   // [4,128]
    const float* Wfc   = (const float*)d_in[7];   // [128,2]
    const float* bfc   = (const float*)d_in[8];
    float* out = (float*)d_out;

    char* ws = (char*)d_ws;
    const size_t BN = (size_t)N_NODES * HID * 2;  // 12.8 MB bf16 plane
    unsigned short* h_bf   = (unsigned short*)(ws);
    unsigned short* xa_bf  = (unsigned short*)(ws + BN);
    unsigned short* xb_bf  = (unsigned short*)(ws + 2 * BN);
    unsigned short* nd_bf  = (unsigned short*)(ws + 3 * BN);
    char* p = ws + 4 * BN;
    unsigned short* wt_hi = (unsigned short*)p;  p += 5 * 16384 * 2;
    unsigned short* wt_lo = (unsigned short*)p;  p += 5 * 16384 * 2;
    float* deg   = (float*)p;            p += N_NODES * 4;
    float* dinv  = (float*)p;            p += N_NODES * 4;
    int*   cnt   = (int*)p;              p += N_NODES * 4;
    int*   offs  = (int*)p;              p += N_NODES * 4;
    int*   cursor= (int*)p;              p += N_NODES * 4;
    int*   bsum  = (int*)p;              p += 1024;
    int2*  epk   = (int2*)p;             p += (size_t)N_EDGES * 8;
    float* cs    = (float*)p;            p += 512;

    const int NB_N = (N_NODES + 255) / 256;   // 196
    const int NB_E = (N_EDGES + 255) / 256;   // 2344

    hipLaunchKernelGGL(init_k,    dim3(NB_N), dim3(256), 0, stream, deg, cnt, cs, N_NODES);
    hipLaunchKernelGGL(edge_deg_k,dim3(NB_E), dim3(256), 0, stream, edges, attr, deg, cnt);
    hipLaunchKernelGGL(rsqrt_k,   dim3(NB_N), dim3(256), 0, stream, deg, dinv, N_NODES);
    hipLaunchKernelGGL(scan1_k,   dim3(NB_N), dim3(256), 0, stream, cnt, offs, bsum, N_NODES);
    hipLaunchKernelGGL(scan2_k,   dim3(1),    dim3(256), 0, stream, bsum, NB_N);
    hipLaunchKernelGGL(scan3_k,   dim3(NB_N), dim3(256), 0, stream, offs, bsum, cursor, N_NODES);
    hipLaunchKernelGGL(fill_k,    dim3(NB_E), dim3(256), 0, stream, edges, attr, dinv, cursor, epk);
    hipLaunchKernelGGL(prep_w_k,  dim3(320),  dim3(256), 0, stream, W1, Ws, wt_hi, wt_lo);
    hipLaunchKernelGGL(cvt_bf_k,  dim3(6250), dim3(256), 0, stream, node, nd_bf, N_NODES * HID / 4);

    const int GB = (N_NODES + 63) / 64;       // 782
    const int AB = (N_NODES * 64) / 256;      // 12500

    // layer 1
    hipLaunchKernelGGL(mfma_gemm_k, dim3(GB), dim3(256), 0, stream, nd_bf, wt_hi, wt_lo, h_bf, N_NODES);
    hipLaunchKernelGGL(aggregate_k, dim3(AB), dim3(256), 0, stream, h_bf, offs, epk, dinv,
                       b1, (const unsigned short*)nullptr, xa_bf, N_NODES);

    // 4 residual steps
    unsigned short* xc = xa_bf;
    unsigned short* xn = xb_bf;
    for (int i = 0; i < 4; ++i) {
        hipLaunchKernelGGL(mfma_gemm_k, dim3(GB), dim3(256), 0, stream,
                           xc, wt_hi + (size_t)(i + 1) * 16384, wt_lo + (size_t)(i + 1) * 16384,
                           h_bf, N_NODES);
        hipLaunchKernelGGL(aggregate_k, dim3(AB), dim3(256), 0, stream, h_bf, offs, epk, dinv,
                           bs + (size_t)i * HID, xc, xn, N_NODES);
        unsigned short* t = xc; xc = xn; xn = t;
    }

    hipLaunchKernelGGL(colsum_k, dim3(512), dim3(128), 0, stream, xc, cs, N_NODES);
    hipLaunchKernelGGL(final_k,  dim3(1),   dim3(128), 0, stream, cs, Wfc, bfc, out);
}

// Round 3
// 479.957 us; speedup vs baseline: 1.3604x; 1.1780x over previous
//
#include <hip/hip_runtime.h>

#define N_NODES 50000
#define N_EDGES 600000
#define HID 128

typedef __attribute__((ext_vector_type(8))) short bf16x8;
typedef __attribute__((ext_vector_type(8))) unsigned short u16x8;
typedef __attribute__((ext_vector_type(4))) float f32x4;

__device__ __forceinline__ float bf2f(unsigned short u) {
    return __uint_as_float(((unsigned int)u) << 16);
}
__device__ __forceinline__ unsigned short f2bf(float f) {
    unsigned int u = __float_as_uint(f);
    u = (u + 0x7FFFu + ((u >> 16) & 1u)) >> 16;   // RNE
    return (unsigned short)u;
}

// ---------------- preprocessing ----------------

// degcnt[i]: bits[43:63] = edge count, bits[0:42] = Q32.32 sum of attr (+1.0 self loop)
__global__ __launch_bounds__(256) void init_k(unsigned long long* degcnt, float* cs, int n) {
    int i = blockIdx.x * 256 + threadIdx.x;
    if (i < n) degcnt[i] = 1ull << 32;          // self-loop weight 1.0, count 0
    if (i < HID) cs[i] = 0.0f;
}

__global__ __launch_bounds__(256) void edge_deg_k(const int* __restrict__ edges,
                                                  const float* __restrict__ attr,
                                                  unsigned long long* degcnt) {
    int e = blockIdx.x * 256 + threadIdx.x;
    if (e < N_EDGES) {
        int c = edges[N_EDGES + e];             // target
        unsigned long long enc = (1ull << 43) +
            (unsigned long long)llrintf(attr[e] * 4294967296.0f);
        atomicAdd(&degcnt[c], enc);
    }
}

// scan pass 1, fused with degcnt decode (cnt extract + dinv)
__global__ __launch_bounds__(256) void scan1_k(const unsigned long long* __restrict__ degcnt,
                                               int* offs, int* bsum, float* dinv, int n) {
    __shared__ int s[256];
    int tid = threadIdx.x;
    int i = blockIdx.x * 256 + tid;
    int v = 0;
    if (i < n) {
        unsigned long long dc = degcnt[i];
        v = (int)(dc >> 43);
        float deg = (float)(dc & ((1ull << 43) - 1)) * (1.0f / 4294967296.0f);
        dinv[i] = rsqrtf(deg);
    }
    s[tid] = v; __syncthreads();
    for (int d = 1; d < 256; d <<= 1) {
        int t = (tid >= d) ? s[tid - d] : 0;
        __syncthreads();
        s[tid] += t;
        __syncthreads();
    }
    if (i < n) offs[i] = s[tid] - v;
    if (tid == 255) bsum[blockIdx.x] = s[255];
}

__global__ __launch_bounds__(256) void scan2_k(int* bsum, int nb) {
    __shared__ int s[256];
    int t = threadIdx.x;
    int v = (t < nb) ? bsum[t] : 0;
    s[t] = v; __syncthreads();
    for (int d = 1; d < 256; d <<= 1) {
        int u = (t >= d) ? s[t - d] : 0;
        __syncthreads();
        s[t] += u;
        __syncthreads();
    }
    if (t < nb) bsum[t] = s[t] - v;
}

__global__ __launch_bounds__(256) void scan3_k(int* offs, const int* __restrict__ bsum, int* cursor, int n) {
    int i = blockIdx.x * 256 + threadIdx.x;
    if (i < n) {
        int v = offs[i] + bsum[blockIdx.x];
        offs[i] = v;
        cursor[i] = v;
    }
}

__global__ __launch_bounds__(256) void fill_k(const int* __restrict__ edges,
                                              const float* __restrict__ attr,
                                              const float* __restrict__ dinv,
                                              int* cursor, int2* __restrict__ epk) {
    int e = blockIdx.x * 256 + threadIdx.x;
    if (e < N_EDGES) {
        int r = edges[e];                    // source
        int c = edges[N_EDGES + e];          // target
        float w = dinv[r] * attr[e] * dinv[c];
        int p = atomicAdd(&cursor[c], 1);
        epk[p] = make_int2(r, __float_as_int(w));
    }
}

// W^T bf16 hi/lo split for 5 layers: Wt[l][n][k] = W_l[k][n]
__global__ __launch_bounds__(256) void prep_w_k(const float* __restrict__ W1,
                                                const float* __restrict__ Ws,
                                                unsigned short* __restrict__ Wt_hi,
                                                unsigned short* __restrict__ Wt_lo) {
    int i = blockIdx.x * 256 + threadIdx.x;
    if (i >= 5 * 16384) return;
    int l = i >> 14;
    int r = i & 16383;
    int n = r >> 7;
    int k = r & 127;
    const float* src = (l == 0) ? W1 : (Ws + (size_t)(l - 1) * 16384);
    float w = src[k * 128 + n];
    unsigned short hi = f2bf(w);
    unsigned short lo = f2bf(w - bf2f(hi));
    Wt_hi[i] = hi;
    Wt_lo[i] = lo;
}

// fp32 -> bf16 bulk convert (4 elems/thread)
__global__ __launch_bounds__(256) void cvt_bf_k(const float* __restrict__ x,
                                                unsigned short* __restrict__ y, int n4) {
    int i = blockIdx.x * 256 + threadIdx.x;
    if (i < n4) {
        float4 v = ((const float4*)x)[i];
        ushort4 o;
        o.x = f2bf(v.x); o.y = f2bf(v.y); o.z = f2bf(v.z); o.w = f2bf(v.w);
        ((ushort4*)y)[i] = o;
    }
}

// ---------------- MFMA GEMM: H[n x 128] = A[n x 128] @ (W_hi + W_lo) ----------------

__global__ __launch_bounds__(256) void mfma_gemm_k(const unsigned short* __restrict__ A,
                                                   const unsigned short* __restrict__ Bh,
                                                   const unsigned short* __restrict__ Bl,
                                                   unsigned short* __restrict__ H, int nrows) {
    int wid  = threadIdx.x >> 6;
    int lane = threadIdx.x & 63;
    int row0 = blockIdx.x * 64 + wid * 16;
    int rl = lane & 15;          // A row within tile / B col
    int kg = lane >> 4;          // k-group (8 elems each)

    int row = row0 + rl;
    int ar  = row < nrows ? row : nrows - 1;

    bf16x8 af[4];
    #pragma unroll
    for (int kt = 0; kt < 4; ++kt)
        af[kt] = *(const bf16x8*)(A + (size_t)ar * HID + kt * 32 + kg * 8);

    f32x4 acc[8];
    #pragma unroll
    for (int nt = 0; nt < 8; ++nt) acc[nt] = (f32x4){0.f, 0.f, 0.f, 0.f};

    #pragma unroll
    for (int nt = 0; nt < 8; ++nt) {
        #pragma unroll
        for (int kt = 0; kt < 4; ++kt) {
            size_t boff = (size_t)(nt * 16 + rl) * HID + kt * 32 + kg * 8;
            bf16x8 bh = *(const bf16x8*)(Bh + boff);
            acc[nt] = __builtin_amdgcn_mfma_f32_16x16x32_bf16(af[kt], bh, acc[nt], 0, 0, 0);
            bf16x8 bl = *(const bf16x8*)(Bl + boff);
            acc[nt] = __builtin_amdgcn_mfma_f32_16x16x32_bf16(af[kt], bl, acc[nt], 0, 0, 0);
        }
    }

    // D: col = lane&15, row = (lane>>4)*4 + reg
    #pragma unroll
    for (int nt = 0; nt < 8; ++nt) {
        #pragma unroll
        for (int r = 0; r < 4; ++r) {
            int orow = row0 + kg * 4 + r;
            if (orow < nrows)
                H[(size_t)orow * HID + nt * 16 + rl] = f2bf(acc[nt][r]);
        }
    }
}

// ---------------- aggregation: one wave per node, 4 edges/iter, 16 lanes x 16B per row ----------------

__global__ __launch_bounds__(256) void aggregate_k(const unsigned short* __restrict__ h,
                                                   const int* __restrict__ offs,
                                                   const int2* __restrict__ epk,
                                                   const float* __restrict__ dinv,
                                                   const float* __restrict__ bias,
                                                   const unsigned short* __restrict__ xprev,
                                                   unsigned short* __restrict__ xout, int n) {
    int w = (blockIdx.x * 256 + threadIdx.x) >> 6;
    if (w >= n) return;
    int lane = threadIdx.x & 63;
    int g  = lane >> 4;                      // edge group 0..3
    int c8 = (lane & 15) * 8;                // 8 bf16 columns per lane

    float a[8];
    #pragma unroll
    for (int j = 0; j < 8; ++j) a[j] = 0.f;

    int e0 = offs[w];
    int e1 = (w + 1 < n) ? offs[w + 1] : N_EDGES;

    for (int e = e0 + g; e < e1; e += 4) {
        int2 pk = epk[e];
        float wt = __int_as_float(pk.y);
        u16x8 hv = *(const u16x8*)(h + (size_t)pk.x * HID + c8);
        #pragma unroll
        for (int j = 0; j < 8; ++j)
            a[j] = fmaf(bf2f(hv[j]), wt, a[j]);
    }

    #pragma unroll
    for (int j = 0; j < 8; ++j) a[j] += __shfl_xor(a[j], 16);
    #pragma unroll
    for (int j = 0; j < 8; ++j) a[j] += __shfl_xor(a[j], 32);

    if (g == 0) {
        float di = dinv[w];
        float d2 = di * di;
        u16x8 hw = *(const u16x8*)(h + (size_t)w * HID + c8);
        #pragma unroll
        for (int j = 0; j < 8; ++j)
            a[j] = fmaf(bf2f(hw[j]), d2, a[j]);
        float4 b0 = *(const float4*)(bias + c8);
        float4 b1 = *(const float4*)(bias + c8 + 4);
        a[0] += b0.x; a[1] += b0.y; a[2] += b0.z; a[3] += b0.w;
        a[4] += b1.x; a[5] += b1.y; a[6] += b1.z; a[7] += b1.w;
        if (xprev) {
            u16x8 xp = *(const u16x8*)(xprev + (size_t)w * HID + c8);
            #pragma unroll
            for (int j = 0; j < 8; ++j) a[j] += bf2f(xp[j]);
        }
        u16x8 o;
        #pragma unroll
        for (int j = 0; j < 8; ++j) o[j] = f2bf(fmaxf(a[j], 0.f));
        *(u16x8*)(xout + (size_t)w * HID + c8) = o;
    }
}

// ---------------- final head ----------------

__global__ __launch_bounds__(128) void colsum_k(const unsigned short* __restrict__ x, float* cs, int n) {
    int col = threadIdx.x;  // 128 threads
    float acc = 0.f;
    for (int r = blockIdx.x; r < n; r += gridDim.x)
        acc += bf2f(x[(size_t)r * HID + col]);
    atomicAdd(&cs[col], acc);
}

__global__ __launch_bounds__(128) void final_k(const float* __restrict__ cs,
                                               const float* __restrict__ Wfc,
                                               const float* __restrict__ bfc,
                                               float* __restrict__ out) {
    __shared__ float s0[128], s1[128];
    int k = threadIdx.x;
    float c = cs[k];
    s0[k] = c * Wfc[k * 2 + 0];
    s1[k] = c * Wfc[k * 2 + 1];
    __syncthreads();
    for (int d = 64; d > 0; d >>= 1) {
        if (k < d) { s0[k] += s0[k + d]; s1[k] += s1[k + d]; }
        __syncthreads();
    }
    if (k == 0) {
        out[0] = s0[0] / (float)N_NODES + bfc[0];
        out[1] = s1[0] / (float)N_NODES + bfc[1];
    }
}

// ---------------- host ----------------

extern "C" void kernel_launch(void* const* d_in, const int* in_sizes, int n_in,
                              void* d_out, int out_size, void* d_ws, size_t ws_size,
                              hipStream_t stream) {
    const float* node  = (const float*)d_in[0];
    const int*   edges = (const int*)d_in[1];     // [2, E] int32
    const float* attr  = (const float*)d_in[2];
    const float* W1    = (const float*)d_in[3];
    const float* b1    = (const float*)d_in[4];
    const float* Ws    = (const float*)d_in[5];   // [4,128,128]
    const float* bs    = (const float*)d_in[6];   // [4,128]
    const float* Wfc   = (const float*)d_in[7];   // [128,2]
    const float* bfc   = (const float*)d_in[8];
    float* out = (float*)d_out;

    char* ws = (char*)d_ws;
    const size_t BN = (size_t)N_NODES * HID * 2;  // 12.8 MB bf16 plane
    unsigned short* h_bf   = (unsigned short*)(ws);
    unsigned short* xa_bf  = (unsigned short*)(ws + BN);
    unsigned short* xb_bf  = (unsigned short*)(ws + 2 * BN);
    unsigned short* nd_bf  = (unsigned short*)(ws + 3 * BN);
    char* p = ws + 4 * BN;
    unsigned long long* degcnt = (unsigned long long*)p; p += (size_t)N_NODES * 8;
    float* dinv  = (float*)p;            p += N_NODES * 4;
    int*   offs  = (int*)p;              p += N_NODES * 4;
    int*   cursor= (int*)p;              p += N_NODES * 4;
    int*   bsum  = (int*)p;              p += 1024;
    int2*  epk   = (int2*)p;             p += (size_t)N_EDGES * 8;
    float* cs    = (float*)p;            p += 512;
    unsigned short* wt_hi = (unsigned short*)p;  p += 5 * 16384 * 2;
    unsigned short* wt_lo = (unsigned short*)p;  p += 5 * 16384 * 2;

    const int NB_N = (N_NODES + 255) / 256;   // 196
    const int NB_E = (N_EDGES + 255) / 256;   // 2344

    hipLaunchKernelGGL(init_k,    dim3(NB_N), dim3(256), 0, stream, degcnt, cs, N_NODES);
    hipLaunchKernelGGL(edge_deg_k,dim3(NB_E), dim3(256), 0, stream, edges, attr, degcnt);
    hipLaunchKernelGGL(scan1_k,   dim3(NB_N), dim3(256), 0, stream, degcnt, offs, bsum, dinv, N_NODES);
    hipLaunchKernelGGL(scan2_k,   dim3(1),    dim3(256), 0, stream, bsum, NB_N);
    hipLaunchKernelGGL(scan3_k,   dim3(NB_N), dim3(256), 0, stream, offs, bsum, cursor, N_NODES);
    hipLaunchKernelGGL(fill_k,    dim3(NB_E), dim3(256), 0, stream, edges, attr, dinv, cursor, epk);
    hipLaunchKernelGGL(prep_w_k,  dim3(320),  dim3(256), 0, stream, W1, Ws, wt_hi, wt_lo);
    hipLaunchKernelGGL(cvt_bf_k,  dim3(6250), dim3(256), 0, stream, node, nd_bf, N_NODES * HID / 4);

    const int GB = (N_NODES + 63) / 64;       // 782
    const int AB = (N_NODES * 64) / 256;      // 12500

    // layer 1
    hipLaunchKernelGGL(mfma_gemm_k, dim3(GB), dim3(256), 0, stream, nd_bf, wt_hi, wt_lo, h_bf, N_NODES);
    hipLaunchKernelGGL(aggregate_k, dim3(AB), dim3(256), 0, stream, h_bf, offs, epk, dinv,
                       b1, (const unsigned short*)nullptr, xa_bf, N_NODES);

    // 4 residual steps
    unsigned short* xc = xa_bf;
    unsigned short* xn = xb_bf;
    for (int i = 0; i < 4; ++i) {
        hipLaunchKernelGGL(mfma_gemm_k, dim3(GB), dim3(256), 0, stream,
                           xc, wt_hi + (size_t)(i + 1) * 16384, wt_lo + (size_t)(i + 1) * 16384,
                           h_bf, N_NODES);
        hipLaunchKernelGGL(aggregate_k, dim3(AB), dim3(256), 0, stream, h_bf, offs, epk, dinv,
                           bs + (size_t)i * HID, xc, xn, N_NODES);
        unsigned short* t = xc; xc = xn; xn = t;
    }

    hipLaunchKernelGGL(colsum_k, dim3(512), dim3(128), 0, stream, xc, cs, N_NODES);
    hipLaunchKernelGGL(final_k,  dim3(1),   dim3(128), 0, stream, cs, Wfc, bfc, out);
}